// Round 1
// 82.017 us; speedup vs baseline: 1.0009x; 1.0009x over previous
//
#include <hip/hip_runtime.h>

#define BB   4
#define CCH  256
#define DQ   32
#define NS   4096
#define TI   64
#define TJ   128
#define PTT  64           // proj token tile
#define PSTR 260          // proj LDS row stride in bf16 (520 B: b64 reads 2-way-free)

typedef __attribute__((ext_vector_type(8)))  short          bhalf8;   // 8 bf16 = 4 VGPRs
typedef __attribute__((ext_vector_type(16))) float          f32x16;   // 32x32 C/D
typedef __attribute__((ext_vector_type(8)))  unsigned short u16x8;
typedef __attribute__((ext_vector_type(4)))  unsigned short u16x4;
typedef __attribute__((ext_vector_type(4)))  short          s16x4;
typedef __attribute__((ext_vector_type(4)))  unsigned int   uint4v;

__device__ __forceinline__ unsigned short f2bf(float f) {
    unsigned u = __float_as_uint(f);
    u += 0x7FFFu + ((u >> 16) & 1u);   // RNE
    return (unsigned short)(u >> 16);
}

__device__ __forceinline__ void async_copy16(unsigned short* lds, const unsigned short* g) {
    __builtin_amdgcn_global_load_lds(
        (const __attribute__((address_space(1))) unsigned int*)g,
        (__attribute__((address_space(3))) unsigned int*)lds, 16, 0, 0);
}

// ---------------- projections: bf16 MFMA GEMM ------------------------------
// gamma==0 fast path: out = gamma*attn + x = x exactly -> pure copy; attn
// early-returns.
// gamma!=0: Y[320][N] = [wq;wk;wv][320][256] @ X[256][N] + bias, per batch.
// Grid 256 = b(4) x token-tile(64 of 64 tok). 640 threads = 10 waves, one
// 32-channel row-block each (q=wave0, k=wave1, v=waves2..9). x tile staged
// transposed to LDS bf16 [64 tok][256 k] (row stride 520 B); W frags held in
// registers (read once per block); K=256 in 16 MFMA steps x 2 token-subtiles.
// Outputs: q,k token-major [B][N][32]; v channel-major [B][C][N].
__global__ __launch_bounds__(640) void proj_kernel(
    const float* __restrict__ x,
    const float* __restrict__ wq, const float* __restrict__ bq,
    const float* __restrict__ wk, const float* __restrict__ bk,
    const float* __restrict__ wv, const float* __restrict__ bv,
    const float* __restrict__ gamma, float* __restrict__ out,
    unsigned short* __restrict__ qt, unsigned short* __restrict__ kt,
    unsigned short* __restrict__ vt)
{
    if (gamma[0] == 0.0f) {            // algebraic short-circuit (uniform branch)
        const float4* xs4 = (const float4*)x;
        float4* os = (float4*)out;
        const unsigned NT4 = (unsigned)BB * CCH * NS / 4;   // 1,048,576 float4s
        for (unsigned idx = blockIdx.x * 640u + threadIdx.x; idx < NT4;
             idx += 256u * 640u)
            os[idx] = xs4[idx];
        return;
    }

    __shared__ unsigned short xs[PTT][PSTR];   // 33.3 KB

    const int tid = threadIdx.x;
    const int tt  = blockIdx.x & 63;
    const int b   = blockIdx.x >> 6;
    const int t0  = tt * PTT;

    const float* xb = x + (size_t)b * CCH * NS + t0;

    // ---- stage x tile [256 k][64 tok] fp32 -> LDS transposed bf16 ----------
    // unit: (channel-pair kp, float4 tq); pack (k,k+1) into one b32 write.
    for (int idx = tid; idx < 2048; idx += 640) {
        const int kp = idx >> 4;          // 0..127
        const int tq = idx & 15;          // float4 within 64 tokens
        const float4 a = *(const float4*)(xb + (size_t)(2 * kp) * NS + 4 * tq);
        const float4 c = *(const float4*)(xb + (size_t)(2 * kp + 1) * NS + 4 * tq);
        const float av[4] = {a.x, a.y, a.z, a.w};
        const float cv[4] = {c.x, c.y, c.z, c.w};
#pragma unroll
        for (int j = 0; j < 4; j++) {
            const unsigned p = (unsigned)f2bf(av[j]) | ((unsigned)f2bf(cv[j]) << 16);
            *(unsigned*)&xs[4 * tq + j][2 * kp] = p;
        }
    }

    // ---- per-wave W fragments, kept in 64 VGPRs across the whole tile -----
    const int wid = tid >> 6, l = tid & 63, l31 = l & 31, l5 = l >> 5;
    const float* wsel; const float* bsel; int row0;
    if (wid == 0)      { wsel = wq; bsel = bq; row0 = 0; }
    else if (wid == 1) { wsel = wk; bsel = bk; row0 = 0; }
    else               { wsel = wv; bsel = bv; row0 = (wid - 2) * 32; }

    // A-frag layout (same as attn's kf): lane l31 = m-row, k = 16ks + 8*l5 + e
    const float* wrow = wsel + (size_t)(row0 + l31) * CCH + 8 * l5;
    bhalf8 af[16];
#pragma unroll
    for (int ks = 0; ks < 16; ks++) {
        const float4 w0 = *(const float4*)(wrow + 16 * ks);
        const float4 w1 = *(const float4*)(wrow + 16 * ks + 4);
        bhalf8 f;
        f[0] = (short)f2bf(w0.x); f[1] = (short)f2bf(w0.y);
        f[2] = (short)f2bf(w0.z); f[3] = (short)f2bf(w0.w);
        f[4] = (short)f2bf(w1.x); f[5] = (short)f2bf(w1.y);
        f[6] = (short)f2bf(w1.z); f[7] = (short)f2bf(w1.w);
        af[ks] = f;
    }

    // bias folded into accumulator init: C/D row ch' = (r&3)+8*(r>>2)+4*l5
    f32x16 acc[2];
#pragma unroll
    for (int m = 0; m < 4; m++) {
        const float4 bb4 = *(const float4*)(bsel + row0 + 8 * m + 4 * l5);
        const float bv4[4] = {bb4.x, bb4.y, bb4.z, bb4.w};
#pragma unroll
        for (int j = 0; j < 4; j++) {
            acc[0][4 * m + j] = bv4[j];
            acc[1][4 * m + j] = bv4[j];
        }
    }

    __syncthreads();

    // ---- K-loop: 16 steps x 2 token-subtiles (acc chains give 2-way ILP) --
#pragma unroll
    for (int ks = 0; ks < 16; ks++) {
        const int col = 16 * ks + 8 * l5;
        const s16x4 a0 = *(const s16x4*)&xs[l31][col];
        const s16x4 a1 = *(const s16x4*)&xs[l31][col + 4];
        const s16x4 b0 = *(const s16x4*)&xs[32 + l31][col];
        const s16x4 b1 = *(const s16x4*)&xs[32 + l31][col + 4];
        const bhalf8 x0 = {a0[0], a0[1], a0[2], a0[3], a1[0], a1[1], a1[2], a1[3]};
        const bhalf8 x1 = {b0[0], b0[1], b0[2], b0[3], b1[0], b1[1], b1[2], b1[3]};
        acc[0] = __builtin_amdgcn_mfma_f32_32x32x16_bf16(af[ks], x0, acc[0], 0, 0, 0);
        acc[1] = __builtin_amdgcn_mfma_f32_32x32x16_bf16(af[ks], x1, acc[1], 0, 0, 0);
    }

    // ---- epilogue: D col = token = l31, row = ch' ------------------------
    if (wid < 2) {
        // token-major q/k: regs 4m..4m+3 are 4 consecutive ch' -> 8 B stores
        unsigned short* dstq = (wid == 0 ? qt : kt) + ((size_t)b * NS + t0) * DQ + 4 * l5;
#pragma unroll
        for (int s = 0; s < 2; s++) {
            unsigned short* p = dstq + (size_t)(32 * s + l31) * DQ;
#pragma unroll
            for (int m = 0; m < 4; m++) {
                u16x4 o;
                o[0] = f2bf(acc[s][4 * m + 0]); o[1] = f2bf(acc[s][4 * m + 1]);
                o[2] = f2bf(acc[s][4 * m + 2]); o[3] = f2bf(acc[s][4 * m + 3]);
                *(u16x4*)(p + 8 * m) = o;
            }
        }
    } else {
        // channel-major v: per reg, 32 lanes = 32 consecutive tokens (64 B line)
        unsigned short* dstv = vt + ((size_t)b * CCH + row0) * NS + t0;
#pragma unroll
        for (int s = 0; s < 2; s++)
#pragma unroll
            for (int r = 0; r < 16; r++) {
                const int ch = (r & 3) + 8 * (r >> 2) + 4 * l5;
                dstv[(size_t)ch * NS + 32 * s + l31] = f2bf(acc[s][r]);
            }
    }
}

// ---------------- fused attention ------------------------------------------
// gamma==0: bare early-return (proj already wrote out = x).
// gamma!=0: full path — grid 256 = b(4) x it(64). 8 waves = ibs(2) x jb(4).
//   S^T = K.Q^T per wave (no duplication); P stays in registers via the
//   half-wave-swap transform; each wave accumulates its j-slice over ALL
//   256 channels (8 C/D tiles); V double-buffered via async global->LDS;
//   one barrier per j-tile; jb-partials reduced through LDS at the end.
// No max-subtraction: logits bounded ~|40| << 88 (fp32 exp overflow).
__global__ __launch_bounds__(512) void attn_kernel(
    const unsigned short* __restrict__ qg, const unsigned short* __restrict__ kg,
    const unsigned short* __restrict__ vg, const float* __restrict__ x,
    const float* __restrict__ gamma, float* __restrict__ out)
{
    __shared__ unsigned short vbuf[2][CCH][TJ];   // 128 KB, swizzled 16B granules
    __shared__ float dsum[4][TI];
    __shared__ float dinv[TI];

    const float g0 = gamma[0];
    if (g0 == 0.0f) return;            // out already written by proj fast path

    const int tid = threadIdx.x;
    const int it  = blockIdx.x & 63;
    const int b   = blockIdx.x >> 6;
    const int i0  = it * TI;

    const int w = tid >> 6, l = tid & 63;
    const int l31 = l & 31, l5 = l >> 5;
    const int ibs = w >> 2, jb = w & 3;

    const unsigned short* qb = qg + ((size_t)b * NS + i0 + 32 * ibs) * DQ;
    const unsigned short* kb = kg + (size_t)b * NS * DQ;
    const unsigned short* vb = vg + (size_t)b * CCH * NS;

    // loop-invariant Q B-frags: B[k=d][n=i=l31] from token-major layout
    bhalf8 qa[2];
#pragma unroll
    for (int kh = 0; kh < 2; kh++)
        qa[kh] = *(const bhalf8*)(qb + (size_t)l31 * DQ + kh * 16 + l5 * 8);

    f32x16 acc[8] = {};          // cb = 0..7: out cols c = 32*cb + l31
    float dl = 0.f;

    // prologue: V tile 0 (async DMA) + K frags tile 0
#pragma unroll
    for (int t = 0; t < 8; t++) {
        int r = 32 * w + 4 * t + (l >> 4);
        async_copy16(&vbuf[0][32 * w + 4 * t][0],
                     vb + (size_t)r * NS + (((l & 15) ^ (r & 15)) * 8));
    }
    bhalf8 kf[2], kfn[2];
#pragma unroll
    for (int kh = 0; kh < 2; kh++)
        kf[kh] = *(const bhalf8*)(kb + (size_t)(32 * jb + l31) * DQ + kh * 16 + l5 * 8);

    for (int jt = 0; jt < NS / TJ; jt++) {
        const int buf = jt & 1;
        __syncthreads();   // V(jt) DMA drained (vmcnt0 before barrier); buf^1 reads done

        if (jt + 1 < NS / TJ) {
            const unsigned short* vs = vb + (size_t)(jt + 1) * TJ;
#pragma unroll
            for (int t = 0; t < 8; t++) {
                int r = 32 * w + 4 * t + (l >> 4);
                async_copy16(&vbuf[buf ^ 1][32 * w + 4 * t][0],
                             vs + (size_t)r * NS + (((l & 15) ^ (r & 15)) * 8));
            }
        }

        // S^T = K.Q^T: lane holds col i=l31; rows j=(r&3)+8*(r>>2)+4*l5 (+32jb)
        f32x16 s = {};
        s = __builtin_amdgcn_mfma_f32_32x32x16_bf16(kf[0], qa[0], s, 0, 0, 0);
        s = __builtin_amdgcn_mfma_f32_32x32x16_bf16(kf[1], qa[1], s, 0, 0, 0);

        if (jt + 1 < NS / TJ) {
#pragma unroll
            for (int kh = 0; kh < 2; kh++)
                kfn[kh] = *(const bhalf8*)(kb + (size_t)((jt + 1) * TJ + 32 * jb + l31) * DQ
                                           + kh * 16 + l5 * 8);
        }

        // exp + pack pairs (j,j+1) -> bf16x2 (truncation; P>0 so benign)
        unsigned int pk[8];
#pragma unroll
        for (int t = 0; t < 8; t++) {
            float p0 = __expf(s[2 * t]);
            float p1 = __expf(s[2 * t + 1]);
            dl += p0 + p1;                    // lane's full j-share for i=l31
            pk[t] = __builtin_amdgcn_perm(__float_as_uint(p1), __float_as_uint(p0),
                                          0x07060302u);
        }

        // half-wave swap -> PV A-frags: lane gets k-elems j = 16kh + 8*l5 + e
        uint4v pa4[2];
#pragma unroll
        for (int kh = 0; kh < 2; kh++)
#pragma unroll
            for (int v = 0; v < 2; v++) {
                unsigned int a  = pk[4 * kh + v];
                unsigned int c2 = pk[4 * kh + v + 2];
                unsigned int ta = __shfl_xor(a, 32);
                unsigned int tc = __shfl_xor(c2, 32);
                pa4[kh][v]     = l5 ? tc : a;
                pa4[kh][v + 2] = l5 ? c2 : ta;
            }

        // PV over all 8 c-blocks: D[m=i][n=c] += P[i][j] V[j][c]
#pragma unroll
        for (int cb = 0; cb < 8; cb++) {
            const int c = 32 * cb + l31;
#pragma unroll
            for (int kh = 0; kh < 2; kh++) {
                int gl = 4 * jb + 2 * kh + l5;
                bhalf8 vf = *(const bhalf8*)&vbuf[buf][c][(gl ^ (c & 15)) * 8];
                acc[cb] = __builtin_amdgcn_mfma_f32_32x32x16_bf16(
                    __builtin_bit_cast(bhalf8, pa4[kh]), vf, acc[cb], 0, 0, 0);
            }
        }

        kf[0] = kfn[0]; kf[1] = kfn[1];
    }

    // denominator: combine half-waves, then the 4 jb waves via LDS
    dl += __shfl_xor(dl, 32);
    if (l < 32) dsum[jb][32 * ibs + l31] = dl;
    __syncthreads();                          // PV done everywhere; vbuf reusable
    if (tid < TI)
        dinv[tid] = g0 / (dsum[0][tid] + dsum[1][tid] + dsum[2][tid] + dsum[3][tid]);

    // reduce jb-partials into otile [256 c][64 i] fp32 (quad-swizzled), in vbuf
    float* otile = (float*)&vbuf[0][0][0];
#pragma unroll
    for (int rnd = 0; rnd < 4; rnd++) {
        if (jb == rnd) {
#pragma unroll
            for (int cb = 0; cb < 8; cb++) {
                const int c = 32 * cb + l31;
#pragma unroll
                for (int g = 0; g < 4; g++) {
                    int iq = 8 * ibs + 2 * g + l5;          // i-quad = i/4
                    float* ad = otile + c * 64 + ((iq ^ (c & 15)) << 2);
                    float4 vA = make_float4(acc[cb][4 * g], acc[cb][4 * g + 1],
                                            acc[cb][4 * g + 2], acc[cb][4 * g + 3]);
                    if (rnd == 0) {
                        *(float4*)ad = vA;
                    } else {
                        float4 pr = *(const float4*)ad;
                        pr.x += vA.x; pr.y += vA.y; pr.z += vA.z; pr.w += vA.w;
                        *(float4*)ad = pr;
                    }
                }
            }
        }
        __syncthreads();
    }

    // epilogue: scale by gamma/denom, add x, coalesced float4 stores
#pragma unroll
    for (int r = 0; r < 8; r++) {
        int idx = r * 512 + tid;               // 256 c x 16 i-quads
        int c = idx >> 4, iq = idx & 15;
        float4 o = *(const float4*)(otile + c * 64 + ((iq ^ (c & 15)) << 2));
        o.x *= dinv[iq * 4 + 0]; o.y *= dinv[iq * 4 + 1];
        o.z *= dinv[iq * 4 + 2]; o.w *= dinv[iq * 4 + 3];
        const size_t go = ((size_t)b * CCH + c) * NS + i0 + iq * 4;
        float4 xr = *(const float4*)(x + go);
        o.x += xr.x; o.y += xr.y; o.z += xr.z; o.w += xr.w;
        *(float4*)(out + go) = o;
    }
}

extern "C" void kernel_launch(void* const* d_in, const int* in_sizes, int n_in,
                              void* d_out, int out_size, void* d_ws, size_t ws_size,
                              hipStream_t stream) {
    const float* x     = (const float*)d_in[0];
    const float* wq    = (const float*)d_in[1];
    const float* bq    = (const float*)d_in[2];
    const float* wk    = (const float*)d_in[3];
    const float* bk    = (const float*)d_in[4];
    const float* wv    = (const float*)d_in[5];
    const float* bv    = (const float*)d_in[6];
    const float* gamma = (const float*)d_in[7];
    float* out = (float*)d_out;

    unsigned short* ws = (unsigned short*)d_ws;
    unsigned short* qt = ws;                          // 1 MB  [B][N][32]
    unsigned short* kt = qt + (size_t)BB * NS * DQ;   // 1 MB  [B][N][32]
    unsigned short* vt = kt + (size_t)BB * NS * DQ;   // 8 MB  [B][256][N]

    proj_kernel<<<dim3(256), 640, 0, stream>>>(x, wq, bq, wk, bk, wv, bv, gamma,
                                               out, qt, kt, vt);
    attn_kernel<<<dim3(BB * (NS / TI)), 512, 0, stream>>>(qt, kt, vt, x, gamma, out);
}